// Round 1
// baseline (2648.411 us; speedup 1.0000x reference)
//
#include <hip/hip_runtime.h>
#include <math.h>

#define B_ 64
#define N_ 512
#define P_ 512
#define E_ 128
#define F_ 512
#define L_ 6
#define SQRT_E_INV 0.08838834764831843f

enum { OPC_NONE = 0, OPC_RELU = 1, OPC_SIG = 2, OPC_EXP = 3, OPC_SCORE = 4 };

// ---------------------------------------------------------------------------
// Generic fp32 GEMM: C[b] = epilogue( opA(A[b]) @ Bw[b] + bias )
// Tiles: 128x128 per block, 256 threads, 8x8 per-thread microtile, K-chunk 16.
// OPA: 0 = plain A, 1 = exp(ascale*A), 2 = exp(ascale*A + Am)
// All dims (M, Nc multiples of 128; K multiple of 16) hold for this problem.
// ---------------------------------------------------------------------------
template <int OPA, int OPC>
__launch_bounds__(256, 3) __global__
void gemm_k(const float* __restrict__ A, const float* __restrict__ Bw,
            const float* __restrict__ bias, float* __restrict__ C,
            int K, int lda, int ldb, int ldc,
            long sA, long sB, long sC,
            const float* __restrict__ sc1, const float* __restrict__ sc2, int sc2i,
            const float* __restrict__ Am, long sAm,
            const float* __restrict__ cd, const float* __restrict__ cm)
{
    const int bz = blockIdx.z;
    const float* Ab = A + (long)bz * sA;
    const float* Bb = Bw + (long)bz * sB;
    float* Cb = C + (long)bz * sC;
    const int row0 = blockIdx.x * 128;
    const int col0 = blockIdx.y * 128;

    float ascale = 0.f;
    if (OPA) ascale = sc1[0] * sc2[sc2i];

    __shared__ float As[16][132];   // [k][m], padded to break 4-way write conflicts
    __shared__ float Bs[16][128];   // [k][n]

    float acc[8][8];
#pragma unroll
    for (int i = 0; i < 8; ++i)
#pragma unroll
        for (int j = 0; j < 8; ++j) acc[i][j] = 0.f;

    const int tid = threadIdx.x;
    const int tx = tid & 15, ty = tid >> 4;

    for (int k0 = 0; k0 < K; k0 += 16) {
        // ---- stage A tile (128 rows x 16 k), transposed into LDS ----
#pragma unroll
        for (int i = 0; i < 2; ++i) {
            int s = tid + i * 256;
            int r = s >> 2;
            int kg = (s & 3) << 2;
            float4 a4 = *(const float4*)(Ab + (long)(row0 + r) * lda + (k0 + kg));
            if (OPA == 1) {
                a4.x = __expf(ascale * a4.x);
                a4.y = __expf(ascale * a4.y);
                a4.z = __expf(ascale * a4.z);
                a4.w = __expf(ascale * a4.w);
            } else if (OPA == 2) {
                float4 m4 = *(const float4*)(Am + (long)bz * sAm +
                                             (long)(row0 + r) * lda + (k0 + kg));
                a4.x = __expf(ascale * a4.x + m4.x);
                a4.y = __expf(ascale * a4.y + m4.y);
                a4.z = __expf(ascale * a4.z + m4.z);
                a4.w = __expf(ascale * a4.w + m4.w);
            }
            As[kg + 0][r] = a4.x;
            As[kg + 1][r] = a4.y;
            As[kg + 2][r] = a4.z;
            As[kg + 3][r] = a4.w;
        }
        // ---- stage B tile (16 k x 128 cols) ----
#pragma unroll
        for (int i = 0; i < 2; ++i) {
            int s = tid + i * 256;
            int kk = s >> 5;
            int c4 = (s & 31) << 2;
            *(float4*)&Bs[kk][c4] =
                *(const float4*)(Bb + (long)(k0 + kk) * ldb + (col0 + c4));
        }
        __syncthreads();
#pragma unroll
        for (int kk = 0; kk < 16; ++kk) {
            float4 a0 = *(const float4*)&As[kk][ty * 8];
            float4 a1 = *(const float4*)&As[kk][ty * 8 + 4];
            float4 b0 = *(const float4*)&Bs[kk][tx * 8];
            float4 b1 = *(const float4*)&Bs[kk][tx * 8 + 4];
            float av[8] = {a0.x, a0.y, a0.z, a0.w, a1.x, a1.y, a1.z, a1.w};
            float bv[8] = {b0.x, b0.y, b0.z, b0.w, b1.x, b1.y, b1.z, b1.w};
#pragma unroll
            for (int i = 0; i < 8; ++i)
#pragma unroll
                for (int j = 0; j < 8; ++j)
                    acc[i][j] = fmaf(av[i], bv[j], acc[i][j]);
        }
        __syncthreads();
    }

    float sp = 0.f;
    if (OPC == OPC_SCORE) sp = sc1[0] * sc2[0];

#pragma unroll
    for (int i = 0; i < 8; ++i) {
        int r = ty * 8 + i;
        long base = (long)(row0 + r) * ldc + col0;
#pragma unroll
        for (int jj = 0; jj < 2; ++jj) {
            int c = tx * 8 + jj * 4;
            float4 v;
            v.x = acc[i][jj * 4 + 0];
            v.y = acc[i][jj * 4 + 1];
            v.z = acc[i][jj * 4 + 2];
            v.w = acc[i][jj * 4 + 3];
            if ((OPC == OPC_NONE || OPC == OPC_RELU) && bias) {
                v.x += bias[col0 + c + 0];
                v.y += bias[col0 + c + 1];
                v.z += bias[col0 + c + 2];
                v.w += bias[col0 + c + 3];
            }
            if (OPC == OPC_RELU) {
                v.x = fmaxf(v.x, 0.f); v.y = fmaxf(v.y, 0.f);
                v.z = fmaxf(v.z, 0.f); v.w = fmaxf(v.w, 0.f);
            } else if (OPC == OPC_SIG) {
                v.x = 1.f / (1.f + __expf(-v.x));
                v.y = 1.f / (1.f + __expf(-v.y));
                v.z = 1.f / (1.f + __expf(-v.z));
                v.w = 1.f / (1.f + __expf(-v.w));
            } else if (OPC == OPC_EXP) {
                v.x = __expf(v.x); v.y = __expf(v.y);
                v.z = __expf(v.z); v.w = __expf(v.w);
            } else if (OPC == OPC_SCORE) {
                long idx = (long)bz * sC + base + c;
                float4 cd4 = *(const float4*)(cd + idx);
                float4 cm4 = *(const float4*)(cm + idx);
                v.x = 10.f * tanhf(fmaf(v.x, SQRT_E_INV, sp * cd4.x)) + cm4.x;
                v.y = 10.f * tanhf(fmaf(v.y, SQRT_E_INV, sp * cd4.y)) + cm4.y;
                v.z = 10.f * tanhf(fmaf(v.z, SQRT_E_INV, sp * cd4.z)) + cm4.z;
                v.w = 10.f * tanhf(fmaf(v.w, SQRT_E_INV, sp * cd4.w)) + cm4.w;
            }
            *(float4*)(Cb + base + c) = v;
        }
    }
}

// ---------------------------------------------------------------------------
// InstanceNorm over node dim (axis=1), fused with residual combine.
// MODE 1: val = a + b_sig * w2num/w2den  (w2 = [num|den] interleaved per row)
// MODE 2: val = a + b
// Grid: (B, E/16). Block 256: el = tid&3 (float4 within 16-wide e-chunk),
// no = tid>>2 (64 n-slices of 8 rows). Values stay in registers between
// stats and normalize.
// ---------------------------------------------------------------------------
template <int MODE>
__launch_bounds__(256) __global__
void inorm_k(const float* __restrict__ a, const float* __restrict__ b,
             const float* __restrict__ w2,
             const float* __restrict__ nw, const float* __restrict__ nb,
             float* __restrict__ out)
{
    const int bb = blockIdx.x;
    const int e0 = blockIdx.y * 16;
    const int tid = threadIdx.x;
    const int el = tid & 3, no = tid >> 2;
    const long base = (long)bb * N_ * E_ + e0 + el * 4;

    float4 vals[8];
    float s1x = 0, s1y = 0, s1z = 0, s1w = 0;
    float s2x = 0, s2y = 0, s2z = 0, s2w = 0;
#pragma unroll
    for (int i = 0; i < 8; ++i) {
        int n = no * 8 + i;
        long ad = base + (long)n * E_;
        float4 v;
        float4 xv = *(const float4*)(a + ad);
        if (MODE == 1) {
            float4 sg = *(const float4*)(b + ad);
            long w2b = ((long)bb * N_ + n) * 256 + e0 + el * 4;
            float4 nu = *(const float4*)(w2 + w2b);
            float4 de = *(const float4*)(w2 + w2b + 128);
            v.x = xv.x + sg.x * nu.x / de.x;
            v.y = xv.y + sg.y * nu.y / de.y;
            v.z = xv.z + sg.z * nu.z / de.z;
            v.w = xv.w + sg.w * nu.w / de.w;
        } else {
            float4 yv = *(const float4*)(b + ad);
            v.x = xv.x + yv.x; v.y = xv.y + yv.y;
            v.z = xv.z + yv.z; v.w = xv.w + yv.w;
        }
        vals[i] = v;
        s1x += v.x; s1y += v.y; s1z += v.z; s1w += v.w;
        s2x = fmaf(v.x, v.x, s2x); s2y = fmaf(v.y, v.y, s2y);
        s2z = fmaf(v.z, v.z, s2z); s2w = fmaf(v.w, v.w, s2w);
    }

    __shared__ float4 r1[256], r2[256];
    r1[tid] = make_float4(s1x, s1y, s1z, s1w);
    r2[tid] = make_float4(s2x, s2y, s2z, s2w);
    __syncthreads();
    for (int s = 128; s >= 4; s >>= 1) {
        if (tid < s) {
            float4 u = r1[tid], w = r1[tid + s];
            r1[tid] = make_float4(u.x + w.x, u.y + w.y, u.z + w.z, u.w + w.w);
            float4 p = r2[tid], q = r2[tid + s];
            r2[tid] = make_float4(p.x + q.x, p.y + q.y, p.z + q.z, p.w + q.w);
        }
        __syncthreads();
    }
    __shared__ float4 mu_s[4], rs_s[4];
    if (tid < 4) {
        float4 m = r1[tid], q = r2[tid];
        m.x *= (1.f / N_); m.y *= (1.f / N_); m.z *= (1.f / N_); m.w *= (1.f / N_);
        q.x *= (1.f / N_); q.y *= (1.f / N_); q.z *= (1.f / N_); q.w *= (1.f / N_);
        float4 rs;
        rs.x = rsqrtf(q.x - m.x * m.x + 1e-5f);
        rs.y = rsqrtf(q.y - m.y * m.y + 1e-5f);
        rs.z = rsqrtf(q.z - m.z * m.z + 1e-5f);
        rs.w = rsqrtf(q.w - m.w * m.w + 1e-5f);
        mu_s[tid] = m; rs_s[tid] = rs;
    }
    __syncthreads();
    float4 mu = mu_s[el], rs = rs_s[el];
    float4 w4 = *(const float4*)(nw + e0 + el * 4);
    float4 b4 = *(const float4*)(nb + e0 + el * 4);
#pragma unroll
    for (int i = 0; i < 8; ++i) {
        int n = no * 8 + i;
        long ad = base + (long)n * E_;
        float4 v = vals[i];
        v.x = fmaf((v.x - mu.x) * rs.x, w4.x, b4.x);
        v.y = fmaf((v.y - mu.y) * rs.y, w4.y, b4.y);
        v.z = fmaf((v.z - mu.z) * rs.z, w4.z, b4.z);
        v.w = fmaf((v.w - mu.w) * rs.w, w4.w, b4.w);
        *(float4*)(out + ad) = v;
    }
}

// ---------------------------------------------------------------------------
__global__ void embed_k(const float* __restrict__ data, const float* __restrict__ W,
                        const float* __restrict__ bias, float* __restrict__ x)
{
    long idx = (long)blockIdx.x * 256 + threadIdx.x;  // over B*N*E
    int e = idx & 127;
    long bn = idx >> 7;
    float d0 = data[bn * 2], d1 = data[bn * 2 + 1];
    x[idx] = fmaf(d0, W[e], fmaf(d1, W[128 + e], bias[e]));
}

__global__ void ekv_k(float* __restrict__ y2)
{
    long idx = (long)blockIdx.x * 256 + threadIdx.x;  // over B*N*128
    int e = idx & 127;
    long bn = idx >> 7;
    y2[bn * 256 + e] *= y2[bn * 256 + 128 + e];
}

__launch_bounds__(512) __global__
void gq_k(const float* __restrict__ enc, const float* __restrict__ dWq,
          float* __restrict__ gq)
{
    int b = blockIdx.x;
    int tid = threadIdx.x;
    int e = tid & 127, qd = tid >> 7;
    float s = 0.f;
    for (int n = qd; n < N_; n += 4) s += enc[((long)b * N_ + n) * E_ + e];
    __shared__ float part[512];
    __shared__ float gm[128];
    part[tid] = s;
    __syncthreads();
    if (tid < 128)
        gm[tid] = (part[tid] + part[tid + 128] + part[tid + 256] + part[tid + 384]) *
                  (1.f / N_);
    __syncthreads();
    if (tid < 128) {
        float acc = 0.f;
        for (int kk = 0; kk < 128; ++kk) acc = fmaf(gm[kk], dWq[kk * 128 + tid], acc);
        gq[b * 128 + tid] = acc;
    }
}

__global__ void dec_aft_k(const float* __restrict__ gq, const float* __restrict__ cap,
                          const float* __restrict__ dWq, const float* __restrict__ w2,
                          float* __restrict__ aft)
{
    long idx = (long)blockIdx.x * 256 + threadIdx.x;  // over B*P*E
    int e = idx & 127;
    long bp = idx >> 7;
    int b = (int)(bp >> 9);  // P = 512
    float q = fmaf(cap[bp], dWq[128 * 128 + e], gq[b * 128 + e]);
    float sg = 1.f / (1.f + __expf(-q));
    long w2b = bp * 256 + e;
    aft[idx] = sg * w2[w2b] / w2[w2b + 128];
}

__launch_bounds__(256) __global__
void transpose_k(const float* __restrict__ in, float* __restrict__ outT)
{
    // in [B,N,E] -> outT [B,E,N]
    int b = blockIdx.z;
    int n0 = blockIdx.x * 32, e0 = blockIdx.y * 32;
    __shared__ float t[32][33];
    int j = threadIdx.x & 31, i0 = threadIdx.x >> 5;
    for (int i = i0; i < 32; i += 8)
        t[i][j] = in[((long)b * N_ + n0 + i) * E_ + e0 + j];
    __syncthreads();
    for (int i = i0; i < 32; i += 8)
        outT[((long)b * E_ + e0 + i) * N_ + n0 + j] = t[j][i];
}

__launch_bounds__(256) __global__
void softmax_k(float* __restrict__ out)
{
    int row = blockIdx.x * 4 + (threadIdx.x >> 6);
    int lane = threadIdx.x & 63;
    float* p = out + (long)row * 512 + lane * 8;
    float4 v0 = *(float4*)p;
    float4 v1 = *(float4*)(p + 4);
    float m = fmaxf(fmaxf(fmaxf(v0.x, v0.y), fmaxf(v0.z, v0.w)),
                    fmaxf(fmaxf(v1.x, v1.y), fmaxf(v1.z, v1.w)));
#pragma unroll
    for (int o = 32; o; o >>= 1) m = fmaxf(m, __shfl_xor(m, o));
    v0.x = __expf(v0.x - m); v0.y = __expf(v0.y - m);
    v0.z = __expf(v0.z - m); v0.w = __expf(v0.w - m);
    v1.x = __expf(v1.x - m); v1.y = __expf(v1.y - m);
    v1.z = __expf(v1.z - m); v1.w = __expf(v1.w - m);
    float s = v0.x + v0.y + v0.z + v0.w + v1.x + v1.y + v1.z + v1.w;
#pragma unroll
    for (int o = 32; o; o >>= 1) s += __shfl_xor(s, o);
    float inv = 1.f / s;
    v0.x *= inv; v0.y *= inv; v0.z *= inv; v0.w *= inv;
    v1.x *= inv; v1.y *= inv; v1.z *= inv; v1.w *= inv;
    *(float4*)p = v0;
    *(float4*)(p + 4) = v1;
}

// ---------------------------------------------------------------------------
static void gemm(hipStream_t st, int opa, int opc,
                 const float* A, const float* Bw, const float* bias, float* C,
                 int M, int K, int Nc, int lda, int ldb, int ldc,
                 long sA, long sB, long sC, int nb,
                 const float* sc1, const float* sc2, int sc2i,
                 const float* Am, long sAm, const float* cd, const float* cm)
{
    dim3 g(M / 128, Nc / 128, nb), blk(256);
#define LAUNCH(oa, oc)                                                        \
    gemm_k<oa, oc><<<g, blk, 0, st>>>(A, Bw, bias, C, K, lda, ldb, ldc, sA,  \
                                      sB, sC, sc1, sc2, sc2i, Am, sAm, cd, cm)
    if (opa == 1) { LAUNCH(1, OPC_NONE); return; }
    if (opa == 2) { LAUNCH(2, OPC_NONE); return; }
    switch (opc) {
        case OPC_NONE:  LAUNCH(0, OPC_NONE); break;
        case OPC_RELU:  LAUNCH(0, OPC_RELU); break;
        case OPC_SIG:   LAUNCH(0, OPC_SIG); break;
        case OPC_EXP:   LAUNCH(0, OPC_EXP); break;
        case OPC_SCORE: LAUNCH(0, OPC_SCORE); break;
    }
#undef LAUNCH
}

extern "C" void kernel_launch(void* const* d_in, const int* in_sizes, int n_in,
                              void* d_out, int out_size, void* d_ws, size_t ws_size,
                              hipStream_t stream)
{
    const float* data      = (const float*)d_in[0];
    const float* dist      = (const float*)d_in[1];
    const float* cur_dist  = (const float*)d_in[2];
    const float* capacity  = (const float*)d_in[3];
    const float* ninf      = (const float*)d_in[4];
    const float* log_scale = (const float*)d_in[5];
    const float* emb_W     = (const float*)d_in[6];
    const float* emb_b     = (const float*)d_in[7];
    const float* Wq        = (const float*)d_in[8];
    const float* Wk        = (const float*)d_in[9];
    const float* Wv        = (const float*)d_in[10];
    const float* aft_alpha = (const float*)d_in[11];
    const float* n1_w      = (const float*)d_in[12];
    const float* n1_b      = (const float*)d_in[13];
    const float* ffW1      = (const float*)d_in[14];
    const float* ffb1      = (const float*)d_in[15];
    const float* ffW2      = (const float*)d_in[16];
    const float* ffb2      = (const float*)d_in[17];
    const float* n2_w      = (const float*)d_in[18];
    const float* n2_b      = (const float*)d_in[19];
    const float* dWq       = (const float*)d_in[20];
    const float* dWk       = (const float*)d_in[21];
    const float* dWv       = (const float*)d_in[22];
    const float* dec_alpha = (const float*)d_in[23];
    const float* p_alpha   = (const float*)d_in[24];

    const size_t SZ = (size_t)B_ * N_ * E_;  // 4M floats
    if (ws_size < (7 * SZ + (size_t)B_ * E_) * sizeof(float)) return;  // need ~112MB

    float* ws  = (float*)d_ws;
    float* x   = ws;            // [B,N,E]
    float* h   = ws + 1 * SZ;   // [B,N,E]; decoder: encT [B,E,N]
    float* sq  = ws + 2 * SZ;   // [B,N,E]; decoder: aft [B,P,E]
    float* y2  = ws + 3 * SZ;   // [B,N,2E] = [ekv | ek]
    float* w2  = ws + 5 * SZ;   // [B,N,2E] = [num | den]
    float* ff1 = ws + 2 * SZ;   // [B,N,F] aliases sq..w2 (dead after norm1)
    float* gq  = ws + 7 * SZ;   // [B,E]
    float* out = (float*)d_out;

    const int M = B_ * N_;  // 32768
    const long nul = 0;

    embed_k<<<M * E_ / 256, 256, 0, stream>>>(data, emb_W, emb_b, x);

    for (int l = 0; l < L_; ++l) {
        const float* wq = Wq + (size_t)l * E_ * E_;
        const float* wk = Wk + (size_t)l * E_ * E_;
        const float* wv = Wv + (size_t)l * E_ * E_;
        // q -> sigmoid, v -> y2[:,0:128], k -> exp -> y2[:,128:256]
        gemm(stream, 0, OPC_SIG, x, wq, nullptr, sq, M, E_, E_, E_, E_, E_,
             0, 0, 0, 1, nullptr, nullptr, 0, nullptr, 0, nullptr, nullptr);
        gemm(stream, 0, OPC_NONE, x, wv, nullptr, y2, M, E_, E_, E_, E_, 256,
             0, 0, 0, 1, nullptr, nullptr, 0, nullptr, 0, nullptr, nullptr);
        gemm(stream, 0, OPC_EXP, x, wk, nullptr, y2 + 128, M, E_, E_, E_, E_, 256,
             0, 0, 0, 1, nullptr, nullptr, 0, nullptr, 0, nullptr, nullptr);
        ekv_k<<<M * E_ / 256, 256, 0, stream>>>(y2);
        // [num|den] = exp(ls*alpha*dist) @ [ekv|ek]   (batched over B)
        gemm(stream, 1, OPC_NONE, dist, y2, nullptr, w2, N_, N_, 256, N_, 256, 256,
             (long)N_ * N_, (long)N_ * 256, (long)N_ * 256, B_,
             log_scale, aft_alpha, l, nullptr, 0, nullptr, nullptr);
        // h = inorm(x + sigmoid(q)*num/den)
        inorm_k<1><<<dim3(B_, E_ / 16), 256, 0, stream>>>(
            x, sq, w2, n1_w + (size_t)l * E_, n1_b + (size_t)l * E_, h);
        // ff
        gemm(stream, 0, OPC_RELU, h, ffW1 + (size_t)l * E_ * F_, ffb1 + (size_t)l * F_,
             ff1, M, E_, F_, E_, F_, F_, 0, 0, 0, 1,
             nullptr, nullptr, 0, nullptr, 0, nullptr, nullptr);
        gemm(stream, 0, OPC_NONE, ff1, ffW2 + (size_t)l * F_ * E_, ffb2 + (size_t)l * E_,
             x, M, F_, E_, F_, E_, E_, 0, 0, 0, 1,
             nullptr, nullptr, 0, nullptr, 0, nullptr, nullptr);
        // x = inorm(h + ff2out)   (ff2out staged raw in x, in-place safe)
        inorm_k<2><<<dim3(B_, E_ / 16), 256, 0, stream>>>(
            h, x, nullptr, n2_w + (size_t)l * E_, n2_b + (size_t)l * E_, x);
    }

    // ---- decoder ----  (enc = x)
    transpose_k<<<dim3(N_ / 32, E_ / 32, B_), 256, 0, stream>>>(x, h);  // encT
    gemm(stream, 0, OPC_NONE, x, dWv, nullptr, y2, M, E_, E_, E_, E_, 256,
         0, 0, 0, 1, nullptr, nullptr, 0, nullptr, 0, nullptr, nullptr);
    gemm(stream, 0, OPC_EXP, x, dWk, nullptr, y2 + 128, M, E_, E_, E_, E_, 256,
         0, 0, 0, 1, nullptr, nullptr, 0, nullptr, 0, nullptr, nullptr);
    ekv_k<<<M * E_ / 256, 256, 0, stream>>>(y2);
    gq_k<<<B_, 512, 0, stream>>>(x, dWq, gq);
    // [num|den] = exp(ls*dec_alpha*cur_dist + ninf) @ [ekv|ek]
    gemm(stream, 2, OPC_NONE, cur_dist, y2, nullptr, w2, P_, N_, 256, N_, 256, 256,
         (long)P_ * N_, (long)N_ * 256, (long)P_ * 256, B_,
         log_scale, dec_alpha, 0, ninf, (long)P_ * N_, nullptr, nullptr);
    dec_aft_k<<<B_ * P_ * E_ / 256, 256, 0, stream>>>(gq, capacity, dWq, w2, sq);
    // score = 10*tanh(aft@encT/sqrtE + ls*pa*cur_dist) + ninf  -> d_out
    gemm(stream, 0, OPC_SCORE, sq, h, nullptr, out, P_, E_, N_, E_, N_, N_,
         (long)P_ * E_, (long)E_ * N_, (long)P_ * N_, B_,
         log_scale, p_alpha, 0, nullptr, 0, cur_dist, ninf);
    softmax_k<<<B_ * P_ / 4, 256, 0, stream>>>(out);
}

// Round 2
// 1363.760 us; speedup vs baseline: 1.9420x; 1.9420x over previous
//
#include <hip/hip_runtime.h>
#include <math.h>

#define B_ 64
#define N_ 512
#define P_ 512
#define E_ 128
#define F_ 512
#define L_ 6
#define SQRT_E_INV 0.08838834764831843f

typedef __attribute__((ext_vector_type(8))) short bf8;
typedef __attribute__((ext_vector_type(16))) float f16v;

enum { E_NONE = 0, E_SIG = 1, E_EKV = 2, E_RELU16 = 3, E_BIAS = 4, E_SCORE = 5 };

__device__ inline unsigned short bf16r(float f) {
    unsigned u = __float_as_uint(f);
    u += 0x7fffu + ((u >> 16) & 1u);
    return (unsigned short)(u >> 16);
}
__device__ inline float bf2f(unsigned short h) {
    return __uint_as_float((unsigned)h << 16);
}

struct MMP {
    const void* A0; const void* A1;              // OPA0: ushort hi/lo. OPA1/2: fp32 A, fp32 mask
    const unsigned short* B0; const unsigned short* B1;
    const float* bias;
    float* Cf; unsigned short* C16;
    const float* aux0; const float* aux1;        // EKV: v fp32; SCORE: cur_dist, ninf
    const float* s1; const float* s2; int s2i;
    int K, lda, ldb, ldc;
    long sA, sB, sC;
};

// ---------------------------------------------------------------------------
// MFMA GEMM: C = epi( opA(A) @ B^T_stored )  with B stored [n][k] k-contig.
// 128x128 tile, 256 thr (4 waves, 2x2 of 64x64; each wave 2x2 of 32x32 MFMA).
// AS/BS = number of bf16 planes (2 = hi/lo split). Terms: Ah*Bh [+Ah*Bl +Al*Bh].
// ---------------------------------------------------------------------------
template <int OPA, int OPC, int AS, int BS>
__launch_bounds__(256, 2) __global__ void mm_k(MMP p)
{
    const int tid = threadIdx.x;
    const int lane = tid & 63, wv = tid >> 6;
    const int wm = wv & 1, wn = wv >> 1;
    const int ln = lane & 31, hk = lane >> 5;
    const int bz = blockIdx.z;
    const int row0 = blockIdx.x * 128, col0 = blockIdx.y * 128;

    __shared__ __align__(16) unsigned short As[AS][128][40];
    __shared__ __align__(16) unsigned short Bs[BS][128][40];

    f16v acc[2][2];
#pragma unroll
    for (int a = 0; a < 2; ++a)
#pragma unroll
        for (int b = 0; b < 2; ++b)
#pragma unroll
            for (int q = 0; q < 16; ++q) acc[a][b][q] = 0.f;

    float ascale = 0.f;
    if (OPA) ascale = p.s1[0] * p.s2[p.s2i];

    const int rr = tid >> 2, kq = tid & 3;

    for (int k0 = 0; k0 < p.K; k0 += 32) {
#pragma unroll
        for (int i = 0; i < 2; ++i) {
            int r = rr + i * 64;
            size_t ga = (size_t)bz * p.sA + (size_t)(row0 + r) * p.lda + k0 + kq * 8;
            if (OPA == 0) {
                *(uint4*)&As[0][r][kq * 8] =
                    *(const uint4*)((const unsigned short*)p.A0 + ga);
                if (AS == 2)
                    *(uint4*)&As[1][r][kq * 8] =
                        *(const uint4*)((const unsigned short*)p.A1 + ga);
            } else {
                const float* Af = (const float*)p.A0;
                float fin[8];
                *(float4*)&fin[0] = *(const float4*)(Af + ga);
                *(float4*)&fin[4] = *(const float4*)(Af + ga + 4);
                if (OPA == 2) {
                    const float* Mf = (const float*)p.A1;
                    float mm[8];
                    *(float4*)&mm[0] = *(const float4*)(Mf + ga);
                    *(float4*)&mm[4] = *(const float4*)(Mf + ga + 4);
#pragma unroll
                    for (int j = 0; j < 8; ++j) fin[j] = __expf(fmaf(ascale, fin[j], mm[j]));
                } else {
#pragma unroll
                    for (int j = 0; j < 8; ++j) fin[j] = __expf(ascale * fin[j]);
                }
                uint4 pk;
                pk.x = bf16r(fin[0]) | ((unsigned)bf16r(fin[1]) << 16);
                pk.y = bf16r(fin[2]) | ((unsigned)bf16r(fin[3]) << 16);
                pk.z = bf16r(fin[4]) | ((unsigned)bf16r(fin[5]) << 16);
                pk.w = bf16r(fin[6]) | ((unsigned)bf16r(fin[7]) << 16);
                *(uint4*)&As[0][r][kq * 8] = pk;
            }
            size_t gb = (size_t)bz * p.sB + (size_t)(col0 + r) * p.ldb + k0 + kq * 8;
            *(uint4*)&Bs[0][r][kq * 8] = *(const uint4*)(p.B0 + gb);
            if (BS == 2)
                *(uint4*)&Bs[1][r][kq * 8] = *(const uint4*)(p.B1 + gb);
        }
        __syncthreads();
#pragma unroll
        for (int s = 0; s < 2; ++s) {
            bf8 ah[2], bh[2], al[2], bl[2];
#pragma unroll
            for (int t = 0; t < 2; ++t) {
                ah[t] = *(const bf8*)&As[0][wm * 64 + t * 32 + ln][s * 16 + hk * 8];
                bh[t] = *(const bf8*)&Bs[0][wn * 64 + t * 32 + ln][s * 16 + hk * 8];
                if (AS == 2)
                    al[t] = *(const bf8*)&As[1][wm * 64 + t * 32 + ln][s * 16 + hk * 8];
                if (BS == 2)
                    bl[t] = *(const bf8*)&Bs[1][wn * 64 + t * 32 + ln][s * 16 + hk * 8];
            }
#pragma unroll
            for (int mt = 0; mt < 2; ++mt)
#pragma unroll
                for (int nt = 0; nt < 2; ++nt) {
                    acc[mt][nt] = __builtin_amdgcn_mfma_f32_32x32x16_bf16(
                        ah[mt], bh[nt], acc[mt][nt], 0, 0, 0);
                    if (BS == 2)
                        acc[mt][nt] = __builtin_amdgcn_mfma_f32_32x32x16_bf16(
                            ah[mt], bl[nt], acc[mt][nt], 0, 0, 0);
                    if (AS == 2)
                        acc[mt][nt] = __builtin_amdgcn_mfma_f32_32x32x16_bf16(
                            al[mt], bh[nt], acc[mt][nt], 0, 0, 0);
                }
        }
        __syncthreads();
    }

    // ---- epilogue ----  C/D layout: col=lane&31, row=(reg&3)+8*(reg>>2)+4*(lane>>5)
    float sp = (OPC == E_SCORE) ? p.s1[0] * p.s2[0] : 0.f;
#pragma unroll
    for (int mt = 0; mt < 2; ++mt) {
        const int gm0 = row0 + wm * 64 + mt * 32;
#pragma unroll
        for (int nt = 0; nt < 2; ++nt) {
            const int gn = col0 + wn * 64 + nt * 32 + ln;
            f16v a = acc[mt][nt];
            float bv = 0.f;
            if (OPC == E_RELU16 || OPC == E_BIAS) bv = p.bias[gn];
#pragma unroll
            for (int g = 0; g < 4; ++g) {
                const int rb = gm0 + g * 8 + hk * 4;
                if (OPC == E_NONE || OPC == E_SIG || OPC == E_BIAS) {
#pragma unroll
                    for (int r = 0; r < 4; ++r) {
                        float v = a[g * 4 + r] + bv;
                        if (OPC == E_SIG) v = 1.f / (1.f + __expf(-v));
                        p.Cf[(size_t)bz * p.sC + (size_t)(rb + r) * p.ldc + gn] = v;
                    }
                } else if (OPC == E_RELU16) {
#pragma unroll
                    for (int r = 0; r < 4; ++r) {
                        float v = fmaxf(a[g * 4 + r] + bv, 0.f);
                        p.C16[(size_t)(rb + r) * p.ldc + gn] = bf16r(v);
                    }
                } else if (OPC == E_EKV) {
                    unsigned short hs[4], es[4];
#pragma unroll
                    for (int r = 0; r < 4; ++r) {
                        float ek = __expf(a[g * 4 + r]);
                        float vv = p.aux0[(size_t)(rb + r) * E_ + gn];
                        hs[r] = bf16r(ek * vv);
                        es[r] = bf16r(ek);
                    }
                    const int bb = gm0 >> 9;
                    const int nb = (gm0 & 511) + g * 8 + hk * 4;
                    unsigned short* dst = p.C16 + (size_t)bb * (256 * 512);
                    uint2 u0, u1;
                    u0.x = hs[0] | ((unsigned)hs[1] << 16);
                    u0.y = hs[2] | ((unsigned)hs[3] << 16);
                    u1.x = es[0] | ((unsigned)es[1] << 16);
                    u1.y = es[2] | ((unsigned)es[3] << 16);
                    *(uint2*)(dst + (size_t)gn * 512 + nb) = u0;
                    *(uint2*)(dst + (size_t)(128 + gn) * 512 + nb) = u1;
                } else if (OPC == E_SCORE) {
#pragma unroll
                    for (int r = 0; r < 4; ++r) {
                        size_t ix = (size_t)bz * p.sC + (size_t)(rb + r) * p.ldc + gn;
                        float sc = fmaf(a[g * 4 + r], SQRT_E_INV, sp * p.aux0[ix]);
                        p.Cf[ix] = 10.f * tanhf(sc) + p.aux1[ix];
                    }
                }
            }
        }
    }
}

// ---------------------------------------------------------------------------
// InstanceNorm over nodes, residual fused. Inputs/outputs = bf16 hi/lo pairs.
// MODE1: val = (ah+al) + sq * num/den ;  MODE2: val = (ah+al) + ff2
// ---------------------------------------------------------------------------
template <int MODE>
__launch_bounds__(256) __global__ void inorm_k(
    const unsigned short* __restrict__ ah, const unsigned short* __restrict__ al,
    const float* __restrict__ f1, const float* __restrict__ w2,
    const float* __restrict__ nw, const float* __restrict__ nbv,
    unsigned short* __restrict__ oh, unsigned short* __restrict__ ol)
{
    const int bb = blockIdx.x, e0 = blockIdx.y * 16;
    const int tid = threadIdx.x, el = tid & 3, no = tid >> 2;
    const size_t base = (size_t)bb * N_ * E_ + e0 + el * 4;

    float4 vals[8];
    float s1x = 0, s1y = 0, s1z = 0, s1w = 0;
    float s2x = 0, s2y = 0, s2z = 0, s2w = 0;
#pragma unroll
    for (int i = 0; i < 8; ++i) {
        int n = no * 8 + i;
        size_t ad = base + (size_t)n * E_;
        uint2 h2 = *(const uint2*)(ah + ad);
        uint2 l2 = *(const uint2*)(al + ad);
        float x0 = bf2f((unsigned short)h2.x) + bf2f((unsigned short)l2.x);
        float x1 = bf2f((unsigned short)(h2.x >> 16)) + bf2f((unsigned short)(l2.x >> 16));
        float x2 = bf2f((unsigned short)h2.y) + bf2f((unsigned short)l2.y);
        float x3 = bf2f((unsigned short)(h2.y >> 16)) + bf2f((unsigned short)(l2.y >> 16));
        float4 v;
        if (MODE == 1) {
            float4 sg = *(const float4*)(f1 + ad);
            size_t wb = ((size_t)bb * N_ + n) * 256 + e0 + el * 4;
            float4 nu = *(const float4*)(w2 + wb);
            float4 de = *(const float4*)(w2 + wb + 128);
            v.x = x0 + sg.x * nu.x / de.x;
            v.y = x1 + sg.y * nu.y / de.y;
            v.z = x2 + sg.z * nu.z / de.z;
            v.w = x3 + sg.w * nu.w / de.w;
        } else {
            float4 ff = *(const float4*)(f1 + ad);
            v.x = x0 + ff.x; v.y = x1 + ff.y; v.z = x2 + ff.z; v.w = x3 + ff.w;
        }
        vals[i] = v;
        s1x += v.x; s1y += v.y; s1z += v.z; s1w += v.w;
        s2x = fmaf(v.x, v.x, s2x); s2y = fmaf(v.y, v.y, s2y);
        s2z = fmaf(v.z, v.z, s2z); s2w = fmaf(v.w, v.w, s2w);
    }

    __shared__ float4 r1[256], r2[256];
    r1[tid] = make_float4(s1x, s1y, s1z, s1w);
    r2[tid] = make_float4(s2x, s2y, s2z, s2w);
    __syncthreads();
    for (int s = 128; s >= 4; s >>= 1) {
        if (tid < s) {
            float4 u = r1[tid], w = r1[tid + s];
            r1[tid] = make_float4(u.x + w.x, u.y + w.y, u.z + w.z, u.w + w.w);
            float4 pq = r2[tid], q = r2[tid + s];
            r2[tid] = make_float4(pq.x + q.x, pq.y + q.y, pq.z + q.z, pq.w + q.w);
        }
        __syncthreads();
    }
    __shared__ float4 mu_s[4], rs_s[4];
    if (tid < 4) {
        float4 m = r1[tid], q = r2[tid];
        m.x *= (1.f / N_); m.y *= (1.f / N_); m.z *= (1.f / N_); m.w *= (1.f / N_);
        q.x *= (1.f / N_); q.y *= (1.f / N_); q.z *= (1.f / N_); q.w *= (1.f / N_);
        float4 rs;
        rs.x = rsqrtf(q.x - m.x * m.x + 1e-5f);
        rs.y = rsqrtf(q.y - m.y * m.y + 1e-5f);
        rs.z = rsqrtf(q.z - m.z * m.z + 1e-5f);
        rs.w = rsqrtf(q.w - m.w * m.w + 1e-5f);
        mu_s[tid] = m; rs_s[tid] = rs;
    }
    __syncthreads();
    float4 mu = mu_s[el], rs = rs_s[el];
    float4 w4 = *(const float4*)(nw + e0 + el * 4);
    float4 b4 = *(const float4*)(nbv + e0 + el * 4);
#pragma unroll
    for (int i = 0; i < 8; ++i) {
        size_t ad = base + (size_t)(no * 8 + i) * E_;
        float4 v = vals[i];
        v.x = fmaf((v.x - mu.x) * rs.x, w4.x, b4.x);
        v.y = fmaf((v.y - mu.y) * rs.y, w4.y, b4.y);
        v.z = fmaf((v.z - mu.z) * rs.z, w4.z, b4.z);
        v.w = fmaf((v.w - mu.w) * rs.w, w4.w, b4.w);
        unsigned short h0 = bf16r(v.x), h1 = bf16r(v.y), h2v = bf16r(v.z), h3 = bf16r(v.w);
        unsigned short l0 = bf16r(v.x - bf2f(h0)), l1 = bf16r(v.y - bf2f(h1));
        unsigned short l2v = bf16r(v.z - bf2f(h2v)), l3 = bf16r(v.w - bf2f(h3));
        uint2 ph, pl;
        ph.x = h0 | ((unsigned)h1 << 16); ph.y = h2v | ((unsigned)h3 << 16);
        pl.x = l0 | ((unsigned)l1 << 16); pl.y = l2v | ((unsigned)l3 << 16);
        *(uint2*)(oh + ad) = ph;
        *(uint2*)(ol + ad) = pl;
    }
}

// ---------------------------------------------------------------------------
__global__ void wprep_k(const float* __restrict__ W, unsigned short* __restrict__ Th,
                        unsigned short* __restrict__ Tl, int K, int N)
{
    // W [mat][K][N] -> T [mat][N][K] split hi/lo.  grid (K/32, N/32, nmat)
    const int z = blockIdx.z;
    const float* Wz = W + (size_t)z * K * N;
    unsigned short* Hh = Th + (size_t)z * K * N;
    unsigned short* Hl = Tl + (size_t)z * K * N;
    __shared__ float t[32][33];
    const int j = threadIdx.x & 31, i0 = threadIdx.x >> 5;
    const int k0 = blockIdx.x * 32, n0 = blockIdx.y * 32;
    for (int i = i0; i < 32; i += 8)
        t[i][j] = Wz[(size_t)(k0 + i) * N + n0 + j];
    __syncthreads();
    for (int i = i0; i < 32; i += 8) {
        float v = t[j][i];
        unsigned short h = bf16r(v);
        unsigned short l = bf16r(v - bf2f(h));
        size_t o = (size_t)(n0 + i) * K + k0 + j;
        Hh[o] = h; Hl[o] = l;
    }
}

__global__ void embed_k(const float* __restrict__ data, const float* __restrict__ W,
                        const float* __restrict__ bias,
                        unsigned short* __restrict__ xh, unsigned short* __restrict__ xl)
{
    size_t idx = (size_t)blockIdx.x * 256 + threadIdx.x;
    int e = idx & 127;
    size_t bn = idx >> 7;
    float v = fmaf(data[bn * 2], W[e], fmaf(data[bn * 2 + 1], W[128 + e], bias[e]));
    unsigned short h = bf16r(v);
    xh[idx] = h;
    xl[idx] = bf16r(v - bf2f(h));
}

__launch_bounds__(512) __global__
void gq_k(const unsigned short* __restrict__ xh, const unsigned short* __restrict__ xl,
          const float* __restrict__ dWq, float* __restrict__ gq)
{
    int b = blockIdx.x;
    int tid = threadIdx.x;
    int e = tid & 127, qd = tid >> 7;
    float s = 0.f;
    for (int n = qd; n < N_; n += 4) {
        size_t ix = ((size_t)b * N_ + n) * E_ + e;
        s += bf2f(xh[ix]) + bf2f(xl[ix]);
    }
    __shared__ float part[512];
    __shared__ float gm[128];
    part[tid] = s;
    __syncthreads();
    if (tid < 128)
        gm[tid] = (part[tid] + part[tid + 128] + part[tid + 256] + part[tid + 384]) *
                  (1.f / N_);
    __syncthreads();
    if (tid < 128) {
        float acc = 0.f;
        for (int kk = 0; kk < 128; ++kk) acc = fmaf(gm[kk], dWq[kk * 128 + tid], acc);
        gq[b * 128 + tid] = acc;
    }
}

__global__ void dec_aft_k(const float* __restrict__ gq, const float* __restrict__ cap,
                          const float* __restrict__ dWq, const float* __restrict__ w2,
                          unsigned short* __restrict__ oh, unsigned short* __restrict__ ol)
{
    size_t idx = (size_t)blockIdx.x * 256 + threadIdx.x;
    int e = idx & 127;
    size_t bp = idx >> 7;
    int b = (int)(bp >> 9);
    float q = fmaf(cap[bp], dWq[128 * 128 + e], gq[b * 128 + e]);
    float sg = 1.f / (1.f + __expf(-q));
    float v = sg * w2[bp * 256 + e] / w2[bp * 256 + 128 + e];
    unsigned short h = bf16r(v);
    oh[idx] = h;
    ol[idx] = bf16r(v - bf2f(h));
}

__launch_bounds__(256) __global__ void softmax_k(float* __restrict__ out)
{
    int row = blockIdx.x * 4 + (threadIdx.x >> 6);
    int lane = threadIdx.x & 63;
    float* p = out + (size_t)row * 512 + lane * 8;
    float4 v0 = *(float4*)p;
    float4 v1 = *(float4*)(p + 4);
    float m = fmaxf(fmaxf(fmaxf(v0.x, v0.y), fmaxf(v0.z, v0.w)),
                    fmaxf(fmaxf(v1.x, v1.y), fmaxf(v1.z, v1.w)));
#pragma unroll
    for (int o = 32; o; o >>= 1) m = fmaxf(m, __shfl_xor(m, o));
    v0.x = __expf(v0.x - m); v0.y = __expf(v0.y - m);
    v0.z = __expf(v0.z - m); v0.w = __expf(v0.w - m);
    v1.x = __expf(v1.x - m); v1.y = __expf(v1.y - m);
    v1.z = __expf(v1.z - m); v1.w = __expf(v1.w - m);
    float s = v0.x + v0.y + v0.z + v0.w + v1.x + v1.y + v1.z + v1.w;
#pragma unroll
    for (int o = 32; o; o >>= 1) s += __shfl_xor(s, o);
    float inv = 1.f / s;
    v0.x *= inv; v0.y *= inv; v0.z *= inv; v0.w *= inv;
    v1.x *= inv; v1.y *= inv; v1.z *= inv; v1.w *= inv;
    *(float4*)p = v0;
    *(float4*)(p + 4) = v1;
}

// ---------------------------------------------------------------------------
extern "C" void kernel_launch(void* const* d_in, const int* in_sizes, int n_in,
                              void* d_out, int out_size, void* d_ws, size_t ws_size,
                              hipStream_t stream)
{
    const float* data      = (const float*)d_in[0];
    const float* dist      = (const float*)d_in[1];
    const float* cur_dist  = (const float*)d_in[2];
    const float* capacity  = (const float*)d_in[3];
    const float* ninf      = (const float*)d_in[4];
    const float* log_scale = (const float*)d_in[5];
    const float* emb_W     = (const float*)d_in[6];
    const float* emb_b     = (const float*)d_in[7];
    const float* Wq        = (const float*)d_in[8];
    const float* Wk        = (const float*)d_in[9];
    const float* Wv        = (const float*)d_in[10];
    const float* aft_alpha = (const float*)d_in[11];
    const float* n1_w      = (const float*)d_in[12];
    const float* n1_b      = (const float*)d_in[13];
    const float* ffW1      = (const float*)d_in[14];
    const float* ffb1      = (const float*)d_in[15];
    const float* ffW2      = (const float*)d_in[16];
    const float* ffb2      = (const float*)d_in[17];
    const float* n2_w      = (const float*)d_in[18];
    const float* n2_b      = (const float*)d_in[19];
    const float* dWq       = (const float*)d_in[20];
    const float* dWk       = (const float*)d_in[21];
    const float* dWv       = (const float*)d_in[22];
    const float* dec_alpha = (const float*)d_in[23];
    const float* p_alpha   = (const float*)d_in[24];
    float* out = (float*)d_out;

    char* W = (char*)d_ws;
    size_t off = 0;
    auto take = [&](size_t n) { void* pp = W + off; off += (n + 255) & ~(size_t)255; return pp; };
    const size_t SZ16 = (size_t)B_ * N_ * E_ * 2;      // 8 MB (bf16 plane)
    const size_t SZ32 = (size_t)B_ * N_ * E_ * 4;      // 16 MB (fp32)

    unsigned short* xh = (unsigned short*)take(SZ16);
    unsigned short* xl = (unsigned short*)take(SZ16);
    unsigned short* hh = (unsigned short*)take(SZ16);  // decoder: aft_hi
    unsigned short* hl = (unsigned short*)take(SZ16);  // decoder: aft_lo
    float* sq  = (float*)take(SZ32);                   // alias: ff2
    float* w2  = (float*)take(2 * SZ32);               // alias: v (first 16MB), ff1 (bf16, 32MB)
    unsigned short* y2t = (unsigned short*)take(SZ32); // [B][256][512] bf16 = 16 MB
    unsigned short* wqt_h = (unsigned short*)take(196608);
    unsigned short* wqt_l = (unsigned short*)take(196608);
    unsigned short* wkt_h = (unsigned short*)take(196608);
    unsigned short* wkt_l = (unsigned short*)take(196608);
    unsigned short* wvt_h = (unsigned short*)take(196608);
    unsigned short* wvt_l = (unsigned short*)take(196608);
    unsigned short* w1t_h = (unsigned short*)take(786432);
    unsigned short* w1t_l = (unsigned short*)take(786432);
    unsigned short* w2t_h = (unsigned short*)take(786432);
    unsigned short* w2t_l = (unsigned short*)take(786432);
    unsigned short* dkt_h = (unsigned short*)take(32768);
    unsigned short* dkt_l = (unsigned short*)take(32768);
    unsigned short* dvt_h = (unsigned short*)take(32768);
    unsigned short* dvt_l = (unsigned short*)take(32768);
    float* gq = (float*)take(32768);
    if (ws_size < off) return;

    float* vbuf = w2;                      // v fp32 (dead before w2 written)
    unsigned short* ff1 = (unsigned short*)w2;  // ff1 bf16 (w2 dead after inorm1)
    float* ff2 = sq;                       // sq dead after inorm1

    // ---- weight prep ----
    wprep_k<<<dim3(4, 4, 6), 256, 0, stream>>>(Wq, wqt_h, wqt_l, 128, 128);
    wprep_k<<<dim3(4, 4, 6), 256, 0, stream>>>(Wk, wkt_h, wkt_l, 128, 128);
    wprep_k<<<dim3(4, 4, 6), 256, 0, stream>>>(Wv, wvt_h, wvt_l, 128, 128);
    wprep_k<<<dim3(4, 16, 6), 256, 0, stream>>>(ffW1, w1t_h, w1t_l, 128, 512);
    wprep_k<<<dim3(16, 4, 6), 256, 0, stream>>>(ffW2, w2t_h, w2t_l, 512, 128);
    wprep_k<<<dim3(4, 4, 1), 256, 0, stream>>>(dWk, dkt_h, dkt_l, 128, 128);
    wprep_k<<<dim3(4, 4, 1), 256, 0, stream>>>(dWv, dvt_h, dvt_l, 128, 128);

    embed_k<<<16384, 256, 0, stream>>>(data, emb_W, emb_b, xh, xl);

    for (int l = 0; l < L_; ++l) {
        MMP p{};
        // q = sigmoid(x@Wq) -> sq
        p = MMP{}; p.A0 = xh; p.A1 = xl; p.B0 = wqt_h + l * 16384; p.B1 = wqt_l + l * 16384;
        p.Cf = sq; p.K = 128; p.lda = 128; p.ldb = 128; p.ldc = 128;
        mm_k<0, E_SIG, 2, 2><<<dim3(256, 1, 1), 256, 0, stream>>>(p);
        // v = x@Wv -> vbuf
        p = MMP{}; p.A0 = xh; p.A1 = xl; p.B0 = wvt_h + l * 16384; p.B1 = wvt_l + l * 16384;
        p.Cf = vbuf; p.K = 128; p.lda = 128; p.ldb = 128; p.ldc = 128;
        mm_k<0, E_NONE, 2, 2><<<dim3(256, 1, 1), 256, 0, stream>>>(p);
        // k = x@Wk -> exp -> y2t (ekv | ek), transposed split
        p = MMP{}; p.A0 = xh; p.A1 = xl; p.B0 = wkt_h + l * 16384; p.B1 = wkt_l + l * 16384;
        p.C16 = y2t; p.aux0 = vbuf; p.K = 128; p.lda = 128; p.ldb = 128; p.ldc = 128;
        mm_k<0, E_EKV, 2, 2><<<dim3(256, 1, 1), 256, 0, stream>>>(p);
        // [num|den] = exp(ls*alpha*dist) @ y2t -> w2
        p = MMP{}; p.A0 = dist; p.B0 = y2t; p.Cf = w2;
        p.s1 = log_scale; p.s2 = aft_alpha; p.s2i = l;
        p.K = 512; p.lda = 512; p.ldb = 512; p.ldc = 256;
        p.sA = 262144; p.sB = 131072; p.sC = 131072;
        mm_k<1, E_NONE, 1, 1><<<dim3(4, 2, 64), 256, 0, stream>>>(p);
        // h = inorm(x + sq*num/den)
        inorm_k<1><<<dim3(B_, 8), 256, 0, stream>>>(
            xh, xl, sq, w2, n1_w + l * 128, n1_b + l * 128, hh, hl);
        // ff1 = relu(h@W1 + b1) (bf16 single)
        p = MMP{}; p.A0 = hh; p.A1 = hl; p.B0 = w1t_h + l * 65536; p.B1 = w1t_l + l * 65536;
        p.bias = ffb1 + l * 512; p.C16 = ff1;
        p.K = 128; p.lda = 128; p.ldb = 128; p.ldc = 512;
        mm_k<0, E_RELU16, 2, 2><<<dim3(256, 4, 1), 256, 0, stream>>>(p);
        // ff2 = ff1@W2 + b2 (A single, B split)
        p = MMP{}; p.A0 = ff1; p.B0 = w2t_h + l * 65536; p.B1 = w2t_l + l * 65536;
        p.bias = ffb2 + l * 128; p.Cf = ff2;
        p.K = 512; p.lda = 512; p.ldb = 512; p.ldc = 128;
        mm_k<0, E_BIAS, 1, 2><<<dim3(256, 1, 1), 256, 0, stream>>>(p);
        // x = inorm(h + ff2)
        inorm_k<2><<<dim3(B_, 8), 256, 0, stream>>>(
            hh, hl, ff2, nullptr, n2_w + l * 128, n2_b + l * 128, xh, xl);
    }

    // ---- decoder ----  (enc = xh/xl)
    {
        MMP p{};
        p = MMP{}; p.A0 = xh; p.A1 = xl; p.B0 = dvt_h; p.B1 = dvt_l;
        p.Cf = vbuf; p.K = 128; p.lda = 128; p.ldb = 128; p.ldc = 128;
        mm_k<0, E_NONE, 2, 2><<<dim3(256, 1, 1), 256, 0, stream>>>(p);
        p = MMP{}; p.A0 = xh; p.A1 = xl; p.B0 = dkt_h; p.B1 = dkt_l;
        p.C16 = y2t; p.aux0 = vbuf; p.K = 128; p.lda = 128; p.ldb = 128; p.ldc = 128;
        mm_k<0, E_EKV, 2, 2><<<dim3(256, 1, 1), 256, 0, stream>>>(p);
        gq_k<<<B_, 512, 0, stream>>>(xh, xl, dWq, gq);
        // [num|den] = exp(ls*da*cur_dist + ninf) @ y2t -> w2
        p = MMP{}; p.A0 = cur_dist; p.A1 = ninf; p.B0 = y2t; p.Cf = w2;
        p.s1 = log_scale; p.s2 = dec_alpha; p.s2i = 0;
        p.K = 512; p.lda = 512; p.ldb = 512; p.ldc = 256;
        p.sA = 262144; p.sB = 131072; p.sC = 131072;
        mm_k<2, E_NONE, 1, 1><<<dim3(4, 2, 64), 256, 0, stream>>>(p);
        dec_aft_k<<<16384, 256, 0, stream>>>(gq, capacity, dWq, w2, hh, hl);
        // score -> out
        p = MMP{}; p.A0 = hh; p.A1 = hl; p.B0 = xh; p.B1 = xl;
        p.Cf = out; p.aux0 = cur_dist; p.aux1 = ninf;
        p.s1 = log_scale; p.s2 = p_alpha; p.s2i = 0;
        p.K = 128; p.lda = 128; p.ldb = 128; p.ldc = 512;
        p.sA = 65536; p.sB = 65536; p.sC = 262144;
        mm_k<0, E_SCORE, 2, 2><<<dim3(4, 4, 64), 256, 0, stream>>>(p);
        softmax_k<<<8192, 256, 0, stream>>>(out);
    }
}

// Round 3
// 1303.818 us; speedup vs baseline: 2.0313x; 1.0460x over previous
//
#include <hip/hip_runtime.h>
#include <math.h>

#define B_ 64
#define N_ 512
#define P_ 512
#define E_ 128
#define F_ 512
#define L_ 6
#define SQRT_E_INV 0.08838834764831843f

typedef unsigned short u16;
typedef __attribute__((ext_vector_type(8))) short bf8;
typedef __attribute__((ext_vector_type(16))) float f16v;

__device__ inline u16 bf16r(float f) {
    unsigned u = __float_as_uint(f);
    u += 0x7fffu + ((u >> 16) & 1u);
    return (u16)(u >> 16);
}
__device__ inline float bf2f(u16 h) { return __uint_as_float((unsigned)h << 16); }

#define MFMA(a, b, c) __builtin_amdgcn_mfma_f32_32x32x16_bf16(a, b, c, 0, 0, 0)

// ===========================================================================
// qvk_k: fused q/v/k (QOFF=0) or decoder v/k (QOFF=1). Tile 64x128, K=128.
// A = x hi/lo split, B = weight hi/lo split (3 MFMA terms).
// Epilogue by blockIdx.y+QOFF: 0 = sigmoid->sq16[n][e], 1 = v->vt[b][e][n],
// 2 = exp->y2t[b][128+e][n].
// ===========================================================================
struct QP {
    const u16 *A0, *A1;
    const u16 *bh0, *bh1, *bh2, *bl0, *bl1, *bl2;
    u16 *sq16, *vt, *y2t;
};

template <int QOFF>
__launch_bounds__(256, 4) __global__ void qvk_k(QP p)
{
    const int tid = threadIdx.x;
    const int lane = tid & 63, wv = tid >> 6;
    const int wm = wv & 1, wn = wv >> 1;
    const int ln = lane & 31, hk = lane >> 5;
    const int row0 = blockIdx.x * 64;
    const int y = blockIdx.y;
    const u16* B0 = (y == 0) ? p.bh0 : (y == 1 ? p.bh1 : p.bh2);
    const u16* B1 = (y == 0) ? p.bl0 : (y == 1 ? p.bl1 : p.bl2);

    __shared__ __align__(16) u16 As[2][64][40];
    __shared__ __align__(16) u16 Bs[2][128][40];

    f16v acc[2];
#pragma unroll
    for (int nt = 0; nt < 2; ++nt)
#pragma unroll
        for (int q = 0; q < 16; ++q) acc[nt][q] = 0.f;

    const int r = tid >> 2, kq = tid & 3;
    for (int k0 = 0; k0 < 128; k0 += 32) {
        size_t ga = (size_t)(row0 + r) * 128 + k0 + kq * 8;
        *(uint4*)&As[0][r][kq * 8] = *(const uint4*)(p.A0 + ga);
        *(uint4*)&As[1][r][kq * 8] = *(const uint4*)(p.A1 + ga);
#pragma unroll
        for (int i = 0; i < 2; ++i) {
            int s = tid + i * 256;
            int rb = s >> 2, q = s & 3;
            size_t gb = (size_t)rb * 128 + k0 + q * 8;
            *(uint4*)&Bs[0][rb][q * 8] = *(const uint4*)(B0 + gb);
            *(uint4*)&Bs[1][rb][q * 8] = *(const uint4*)(B1 + gb);
        }
        __syncthreads();
#pragma unroll
        for (int s = 0; s < 2; ++s) {
            bf8 ah = *(const bf8*)&As[0][wm * 32 + ln][s * 16 + hk * 8];
            bf8 al = *(const bf8*)&As[1][wm * 32 + ln][s * 16 + hk * 8];
#pragma unroll
            for (int nt = 0; nt < 2; ++nt) {
                bf8 bh = *(const bf8*)&Bs[0][wn * 64 + nt * 32 + ln][s * 16 + hk * 8];
                bf8 bl = *(const bf8*)&Bs[1][wn * 64 + nt * 32 + ln][s * 16 + hk * 8];
                acc[nt] = MFMA(ah, bh, acc[nt]);
                acc[nt] = MFMA(ah, bl, acc[nt]);
                acc[nt] = MFMA(al, bh, acc[nt]);
            }
        }
        __syncthreads();
    }

    const int eid = y + QOFF;
#pragma unroll
    for (int nt = 0; nt < 2; ++nt) {
        int gn = wn * 64 + nt * 32 + ln;
#pragma unroll
        for (int g = 0; g < 4; ++g) {
            int rb = row0 + wm * 32 + g * 8 + hk * 4;
            if (eid == 0) {
#pragma unroll
                for (int rr = 0; rr < 4; ++rr) {
                    float v = acc[nt][g * 4 + rr];
                    v = 1.f / (1.f + __expf(-v));
                    p.sq16[(size_t)(rb + rr) * 128 + gn] = bf16r(v);
                }
            } else {
                int bb = rb >> 9, nb = rb & 511;
                u16 q4[4];
#pragma unroll
                for (int rr = 0; rr < 4; ++rr) {
                    float v = acc[nt][g * 4 + rr];
                    if (eid == 2) v = __expf(v);
                    q4[rr] = bf16r(v);
                }
                uint2 u;
                u.x = q4[0] | ((unsigned)q4[1] << 16);
                u.y = q4[2] | ((unsigned)q4[3] << 16);
                u16* dst = (eid == 1)
                    ? (p.vt + (size_t)bb * 65536 + (size_t)gn * 512 + nb)
                    : (p.y2t + (size_t)bb * 131072 + (size_t)(128 + gn) * 512 + nb);
                *(uint2*)dst = u;
            }
        }
    }
}

// ===========================================================================
// ffn_k: PH=1: ff1 = relu(h@W1+b1) -> bf16 [n][512]; PH=2: ff2 = ff1@W2+b2 -> f32
// ===========================================================================
struct FP {
    const u16 *A0, *A1;
    const u16 *B0, *B1;
    const float* bias;
    u16* o16; float* of;
};

template <int PH>
__launch_bounds__(256, 4) __global__ void ffn_k(FP p)
{
    constexpr int AS = (PH == 1) ? 2 : 1;
    constexpr int K = (PH == 1) ? 128 : 512;
    const int tid = threadIdx.x;
    const int lane = tid & 63, wv = tid >> 6;
    const int wm = wv & 1, wn = wv >> 1;
    const int ln = lane & 31, hk = lane >> 5;
    const int row0 = blockIdx.x * 64;
    const int colB0 = blockIdx.y * 128;

    __shared__ __align__(16) u16 As[AS][64][40];
    __shared__ __align__(16) u16 Bs[2][128][40];

    f16v acc[2];
#pragma unroll
    for (int nt = 0; nt < 2; ++nt)
#pragma unroll
        for (int q = 0; q < 16; ++q) acc[nt][q] = 0.f;

    const int r = tid >> 2, kq = tid & 3;
    for (int k0 = 0; k0 < K; k0 += 32) {
        size_t ga = (size_t)(row0 + r) * K + k0 + kq * 8;
        *(uint4*)&As[0][r][kq * 8] = *(const uint4*)(p.A0 + ga);
        if (AS == 2) *(uint4*)&As[1][r][kq * 8] = *(const uint4*)(p.A1 + ga);
#pragma unroll
        for (int i = 0; i < 2; ++i) {
            int s = tid + i * 256;
            int rb = s >> 2, q = s & 3;
            size_t gb = (size_t)(colB0 + rb) * K + k0 + q * 8;
            *(uint4*)&Bs[0][rb][q * 8] = *(const uint4*)(p.B0 + gb);
            *(uint4*)&Bs[1][rb][q * 8] = *(const uint4*)(p.B1 + gb);
        }
        __syncthreads();
#pragma unroll
        for (int s = 0; s < 2; ++s) {
            bf8 ah = *(const bf8*)&As[0][wm * 32 + ln][s * 16 + hk * 8];
            bf8 al;
            if (AS == 2) al = *(const bf8*)&As[1][wm * 32 + ln][s * 16 + hk * 8];
#pragma unroll
            for (int nt = 0; nt < 2; ++nt) {
                bf8 bh = *(const bf8*)&Bs[0][wn * 64 + nt * 32 + ln][s * 16 + hk * 8];
                bf8 bl = *(const bf8*)&Bs[1][wn * 64 + nt * 32 + ln][s * 16 + hk * 8];
                acc[nt] = MFMA(ah, bh, acc[nt]);
                acc[nt] = MFMA(ah, bl, acc[nt]);
                if (AS == 2) acc[nt] = MFMA(al, bh, acc[nt]);
            }
        }
        __syncthreads();
    }

#pragma unroll
    for (int nt = 0; nt < 2; ++nt) {
        int gcol = colB0 + wn * 64 + nt * 32 + ln;
        float bv = p.bias[gcol];
#pragma unroll
        for (int g = 0; g < 4; ++g) {
            int rb = row0 + wm * 32 + g * 8 + hk * 4;
#pragma unroll
            for (int rr = 0; rr < 4; ++rr) {
                float v = acc[nt][g * 4 + rr] + bv;
                if (PH == 1) {
                    v = fmaxf(v, 0.f);
                    p.o16[(size_t)(rb + rr) * 512 + gcol] = bf16r(v);
                } else {
                    p.of[(size_t)(rb + rr) * 128 + gcol] = v;
                }
            }
        }
    }
}

// ===========================================================================
// big_k: batched big-K GEMM, tile 64x256 (4 waves = 2x2, wave 32x128, nt=4).
// OPA1: A=exp(as*fp32), OPA2: A=exp(as*fp32+mask), OPA0: A=bf16 hi/lo.
// OPC0: fp32 out [512][256] (w2); OPC1: score epilogue -> out.
// ===========================================================================
struct GP {
    const void *A0, *A1;
    const u16 *B0, *B1;
    float* Cf;
    const float *cd, *cm;
    const float *s1, *s2; int s2i;
    int K, lda, ldb;
    long sA, sB;
};

template <int OPA, int OPC>
__launch_bounds__(256, OPC ? 3 : 4) __global__ void big_k(GP p)
{
    constexpr int AS = (OPA == 0) ? 2 : 1;
    constexpr int BS = (OPC == 1) ? 2 : 1;
    const int tid = threadIdx.x;
    const int lane = tid & 63, wv = tid >> 6;
    const int wm = wv & 1, wn = wv >> 1;
    const int ln = lane & 31, hk = lane >> 5;
    const int row0 = blockIdx.x * 64;
    const int colB0 = blockIdx.y * 256;
    const int bz = blockIdx.z;

    __shared__ __align__(16) u16 As[AS][64][40];
    __shared__ __align__(16) u16 Bs[BS][256][40];

    f16v acc[4];
#pragma unroll
    for (int nt = 0; nt < 4; ++nt)
#pragma unroll
        for (int q = 0; q < 16; ++q) acc[nt][q] = 0.f;

    float ascale = 0.f;
    if (OPA) ascale = p.s1[0] * p.s2[p.s2i];

    const int r = tid >> 2, kq = tid & 3;
    for (int k0 = 0; k0 < p.K; k0 += 32) {
        if (OPA == 0) {
            size_t ga = (size_t)bz * p.sA + (size_t)(row0 + r) * p.lda + k0 + kq * 8;
            *(uint4*)&As[0][r][kq * 8] = *(const uint4*)((const u16*)p.A0 + ga);
            *(uint4*)&As[AS - 1][r][kq * 8] = *(const uint4*)((const u16*)p.A1 + ga);
        } else {
            size_t ga = (size_t)bz * p.sA + (size_t)(row0 + r) * p.lda + k0 + kq * 8;
            const float* Af = (const float*)p.A0;
            float f[8];
            *(float4*)&f[0] = *(const float4*)(Af + ga);
            *(float4*)&f[4] = *(const float4*)(Af + ga + 4);
            if (OPA == 2) {
                const float* Mf = (const float*)p.A1;
                float m[8];
                *(float4*)&m[0] = *(const float4*)(Mf + ga);
                *(float4*)&m[4] = *(const float4*)(Mf + ga + 4);
#pragma unroll
                for (int j = 0; j < 8; ++j) f[j] = __expf(fmaf(ascale, f[j], m[j]));
            } else {
#pragma unroll
                for (int j = 0; j < 8; ++j) f[j] = __expf(ascale * f[j]);
            }
            uint4 pk;
            pk.x = bf16r(f[0]) | ((unsigned)bf16r(f[1]) << 16);
            pk.y = bf16r(f[2]) | ((unsigned)bf16r(f[3]) << 16);
            pk.z = bf16r(f[4]) | ((unsigned)bf16r(f[5]) << 16);
            pk.w = bf16r(f[6]) | ((unsigned)bf16r(f[7]) << 16);
            *(uint4*)&As[0][r][kq * 8] = pk;
        }
#pragma unroll
        for (int i = 0; i < 4; ++i) {
            size_t gb = (size_t)bz * p.sB + (size_t)(colB0 + tid) * p.ldb + k0 + i * 8;
            *(uint4*)&Bs[0][tid][i * 8] = *(const uint4*)(p.B0 + gb);
            if (BS == 2) *(uint4*)&Bs[1][tid][i * 8] = *(const uint4*)(p.B1 + gb);
        }
        __syncthreads();
#pragma unroll
        for (int s = 0; s < 2; ++s) {
            bf8 ah = *(const bf8*)&As[0][wm * 32 + ln][s * 16 + hk * 8];
            bf8 al;
            if (AS == 2) al = *(const bf8*)&As[1][wm * 32 + ln][s * 16 + hk * 8];
#pragma unroll
            for (int nt = 0; nt < 4; ++nt) {
                bf8 bh = *(const bf8*)&Bs[0][wn * 128 + nt * 32 + ln][s * 16 + hk * 8];
                acc[nt] = MFMA(ah, bh, acc[nt]);
                if (BS == 2) {
                    bf8 bl = *(const bf8*)&Bs[1][wn * 128 + nt * 32 + ln][s * 16 + hk * 8];
                    acc[nt] = MFMA(ah, bl, acc[nt]);
                    if (AS == 2) acc[nt] = MFMA(al, bh, acc[nt]);
                }
            }
        }
        __syncthreads();
    }

    float sp = (OPC == 1) ? p.s1[0] * p.s2[0] : 0.f;
#pragma unroll
    for (int nt = 0; nt < 4; ++nt) {
        int gn = (OPC == 1 ? colB0 : 0) + wn * 128 + nt * 32 + ln;
#pragma unroll
        for (int g = 0; g < 4; ++g) {
            int rb = row0 + wm * 32 + g * 8 + hk * 4;
#pragma unroll
            for (int rr = 0; rr < 4; ++rr) {
                float v = acc[nt][g * 4 + rr];
                if (OPC == 0) {
                    p.Cf[(size_t)bz * 131072 + (size_t)(rb + rr) * 256 + gn] = v;
                } else {
                    size_t ix = (size_t)bz * 262144 + (size_t)(rb + rr) * 512 + gn;
                    float sc = fmaf(v, SQRT_E_INV, sp * p.cd[ix]);
                    float e2 = __expf(2.f * sc);
                    float th = 1.f - 2.f / (e2 + 1.f);
                    p.Cf[ix] = 10.f * th + p.cm[ix];
                }
            }
        }
    }
}

// ===========================================================================
// ekv_k: y2t[b][e][n] = vt[b][e][n] * y2t[b][128+e][n]   (all bf16)
// ===========================================================================
__global__ void ekv_k(const u16* __restrict__ vt, u16* __restrict__ y2t)
{
    size_t t = (size_t)blockIdx.x * 256 + threadIdx.x;   // B*E*N/8 = 512K
    int b = (int)(t >> 13);
    int rem = (int)(t & 8191);
    int e = rem >> 6, n8 = rem & 63;
    const u16* pv = vt + (size_t)b * 65536 + (size_t)e * 512 + n8 * 8;
    const u16* pe = y2t + (size_t)b * 131072 + (size_t)(128 + e) * 512 + n8 * 8;
    u16* pd = y2t + (size_t)b * 131072 + (size_t)e * 512 + n8 * 8;
    uint4 v4 = *(const uint4*)pv;
    uint4 e4 = *(const uint4*)pe;
    const unsigned* vw = (const unsigned*)&v4;
    const unsigned* ew = (const unsigned*)&e4;
    uint4 o;
    unsigned* ow = (unsigned*)&o;
#pragma unroll
    for (int i = 0; i < 4; ++i) {
        float a0 = bf2f((u16)vw[i]) * bf2f((u16)ew[i]);
        float a1 = bf2f((u16)(vw[i] >> 16)) * bf2f((u16)(ew[i] >> 16));
        ow[i] = bf16r(a0) | ((unsigned)bf16r(a1) << 16);
    }
    *(uint4*)pd = o;
}

// ===========================================================================
// InstanceNorm over nodes, residual fused.
// MODE1: val = (ah+al) + sg16 * num/den ; MODE2: val = (ah+al) + ff2(f32)
// ===========================================================================
template <int MODE>
__launch_bounds__(256) __global__ void inorm_k(
    const u16* __restrict__ ah, const u16* __restrict__ al,
    const u16* __restrict__ sg16, const float* __restrict__ f1,
    const float* __restrict__ w2,
    const float* __restrict__ nw, const float* __restrict__ nbv,
    u16* __restrict__ oh, u16* __restrict__ ol)
{
    const int bb = blockIdx.x, e0 = blockIdx.y * 16;
    const int tid = threadIdx.x, el = tid & 3, no = tid >> 2;
    const size_t base = (size_t)bb * N_ * E_ + e0 + el * 4;

    float4 vals[8];
    float s1x = 0, s1y = 0, s1z = 0, s1w = 0;
    float s2x = 0, s2y = 0, s2z = 0, s2w = 0;
#pragma unroll
    for (int i = 0; i < 8; ++i) {
        int n = no * 8 + i;
        size_t ad = base + (size_t)n * E_;
        uint2 h2 = *(const uint2*)(ah + ad);
        uint2 l2 = *(const uint2*)(al + ad);
        float x0 = bf2f((u16)h2.x) + bf2f((u16)l2.x);
        float x1 = bf2f((u16)(h2.x >> 16)) + bf2f((u16)(l2.x >> 16));
        float x2 = bf2f((u16)h2.y) + bf2f((u16)l2.y);
        float x3 = bf2f((u16)(h2.y >> 16)) + bf2f((u16)(l2.y >> 16));
        float4 v;
        if (MODE == 1) {
            uint2 s2v = *(const uint2*)(sg16 + ad);
            float g0 = bf2f((u16)s2v.x), g1 = bf2f((u16)(s2v.x >> 16));
            float g2 = bf2f((u16)s2v.y), g3 = bf2f((u16)(s2v.y >> 16));
            size_t wb = ((size_t)bb * N_ + n) * 256 + e0 + el * 4;
            float4 nu = *(const float4*)(w2 + wb);
            float4 de = *(const float4*)(w2 + wb + 128);
            v.x = x0 + g0 * nu.x / de.x;
            v.y = x1 + g1 * nu.y / de.y;
            v.z = x2 + g2 * nu.z / de.z;
            v.w = x3 + g3 * nu.w / de.w;
        } else {
            float4 ff = *(const float4*)(f1 + ad);
            v.x = x0 + ff.x; v.y = x1 + ff.y; v.z = x2 + ff.z; v.w = x3 + ff.w;
        }
        vals[i] = v;
        s1x += v.x; s1y += v.y; s1z += v.z; s1w += v.w;
        s2x = fmaf(v.x, v.x, s2x); s2y = fmaf(v.y, v.y, s2y);
        s2z = fmaf(v.z, v.z, s2z); s2w = fmaf(v.w, v.w, s2w);
    }

    __shared__ float4 r1[256], r2[256];
    r1[tid] = make_float4(s1x, s1y, s1z, s1w);
    r2[tid] = make_float4(s2x, s2y, s2z, s2w);
    __syncthreads();
    for (int s = 128; s >= 4; s >>= 1) {
        if (tid < s) {
            float4 u = r1[tid], w = r1[tid + s];
            r1[tid] = make_float4(u.x + w.x, u.y + w.y, u.z + w.z, u.w + w.w);
            float4 pq = r2[tid], q = r2[tid + s];
            r2[tid] = make_float4(pq.x + q.x, pq.y + q.y, pq.z + q.z, pq.w + q.w);
        }
        __syncthreads();
    }
    __shared__ float4 mu_s[4], rs_s[4];
    if (tid < 4) {
        float4 m = r1[tid], q = r2[tid];
        m.x *= (1.f / N_); m.y *= (1.f / N_); m.z *= (1.f / N_); m.w *= (1.f / N_);
        q.x *= (1.f / N_); q.y *= (1.f / N_); q.z *= (1.f / N_); q.w *= (1.f / N_);
        float4 rs;
        rs.x = rsqrtf(q.x - m.x * m.x + 1e-5f);
        rs.y = rsqrtf(q.y - m.y * m.y + 1e-5f);
        rs.z = rsqrtf(q.z - m.z * m.z + 1e-5f);
        rs.w = rsqrtf(q.w - m.w * m.w + 1e-5f);
        mu_s[tid] = m; rs_s[tid] = rs;
    }
    __syncthreads();
    float4 mu = mu_s[el], rs = rs_s[el];
    float4 w4 = *(const float4*)(nw + e0 + el * 4);
    float4 b4 = *(const float4*)(nbv + e0 + el * 4);
#pragma unroll
    for (int i = 0; i < 8; ++i) {
        size_t ad = base + (size_t)(no * 8 + i) * E_;
        float4 v = vals[i];
        v.x = fmaf((v.x - mu.x) * rs.x, w4.x, b4.x);
        v.y = fmaf((v.y - mu.y) * rs.y, w4.y, b4.y);
        v.z = fmaf((v.z - mu.z) * rs.z, w4.z, b4.z);
        v.w = fmaf((v.w - mu.w) * rs.w, w4.w, b4.w);
        u16 h0 = bf16r(v.x), h1 = bf16r(v.y), h2v = bf16r(v.z), h3 = bf16r(v.w);
        u16 l0 = bf16r(v.x - bf2f(h0)), l1 = bf16r(v.y - bf2f(h1));
        u16 l2v = bf16r(v.z - bf2f(h2v)), l3 = bf16r(v.w - bf2f(h3));
        uint2 ph, pl;
        ph.x = h0 | ((unsigned)h1 << 16); ph.y = h2v | ((unsigned)h3 << 16);
        pl.x = l0 | ((unsigned)l1 << 16); pl.y = l2v | ((unsigned)l3 << 16);
        *(uint2*)(oh + ad) = ph;
        *(uint2*)(ol + ad) = pl;
    }
}

// ===========================================================================
__global__ void wprep_k(const float* __restrict__ W, u16* __restrict__ Th,
                        u16* __restrict__ Tl, int K, int N)
{
    const int z = blockIdx.z;
    const float* Wz = W + (size_t)z * K * N;
    u16* Hh = Th + (size_t)z * K * N;
    u16* Hl = Tl + (size_t)z * K * N;
    __shared__ float t[32][33];
    const int j = threadIdx.x & 31, i0 = threadIdx.x >> 5;
    const int k0 = blockIdx.x * 32, n0 = blockIdx.y * 32;
    for (int i = i0; i < 32; i += 8)
        t[i][j] = Wz[(size_t)(k0 + i) * N + n0 + j];
    __syncthreads();
    for (int i = i0; i < 32; i += 8) {
        float v = t[j][i];
        u16 h = bf16r(v);
        u16 l = bf16r(v - bf2f(h));
        size_t o = (size_t)(n0 + i) * K + k0 + j;
        Hh[o] = h; Hl[o] = l;
    }
}

__global__ void embed_k(const float* __restrict__ data, const float* __restrict__ W,
                        const float* __restrict__ bias,
                        u16* __restrict__ xh, u16* __restrict__ xl)
{
    size_t idx = (size_t)blockIdx.x * 256 + threadIdx.x;
    int e = idx & 127;
    size_t bn = idx >> 7;
    float v = fmaf(data[bn * 2], W[e], fmaf(data[bn * 2 + 1], W[128 + e], bias[e]));
    u16 h = bf16r(v);
    xh[idx] = h;
    xl[idx] = bf16r(v - bf2f(h));
}

__launch_bounds__(512) __global__
void gq_k(const u16* __restrict__ xh, const u16* __restrict__ xl,
          const float* __restrict__ dWq, float* __restrict__ gq)
{
    int b = blockIdx.x;
    int tid = threadIdx.x;
    int e = tid & 127, qd = tid >> 7;
    float s = 0.f;
    for (int n = qd; n < N_; n += 4) {
        size_t ix = ((size_t)b * N_ + n) * E_ + e;
        s += bf2f(xh[ix]) + bf2f(xl[ix]);
    }
    __shared__ float part[512];
    __shared__ float gm[128];
    part[tid] = s;
    __syncthreads();
    if (tid < 128)
        gm[tid] = (part[tid] + part[tid + 128] + part[tid + 256] + part[tid + 384]) *
                  (1.f / N_);
    __syncthreads();
    if (tid < 128) {
        float acc = 0.f;
        for (int kk = 0; kk < 128; ++kk) acc = fmaf(gm[kk], dWq[kk * 128 + tid], acc);
        gq[b * 128 + tid] = acc;
    }
}

__global__ void dec_aft_k(const float* __restrict__ gq, const float* __restrict__ cap,
                          const float* __restrict__ dWq, const float* __restrict__ w2,
                          u16* __restrict__ oh, u16* __restrict__ ol)
{
    size_t idx = (size_t)blockIdx.x * 256 + threadIdx.x;
    int e = idx & 127;
    size_t bp = idx >> 7;
    int b = (int)(bp >> 9);
    float q = fmaf(cap[bp], dWq[128 * 128 + e], gq[b * 128 + e]);
    float sg = 1.f / (1.f + __expf(-q));
    float v = sg * w2[bp * 256 + e] / w2[bp * 256 + 128 + e];
    u16 h = bf16r(v);
    oh[idx] = h;
    ol[idx] = bf16r(v - bf2f(h));
}

__launch_bounds__(256) __global__ void softmax_k(float* __restrict__ out)
{
    int row = blockIdx.x * 4 + (threadIdx.x >> 6);
    int lane = threadIdx.x & 63;
    float* p = out + (size_t)row * 512 + lane * 8;
    float4 v0 = *(float4*)p;
    float4 v1 = *(float4*)(p + 4);
    float m = fmaxf(fmaxf(fmaxf(v0.x, v0.y), fmaxf(v0.z, v0.w)),
                    fmaxf(fmaxf(v1.x, v1.y), fmaxf(v1.z, v1.w)));
#pragma unroll
    for (int o = 32; o; o >>= 1) m = fmaxf(m, __shfl_xor(m, o));
    v0.x = __expf(v0.x - m); v0.y = __expf(v0.y - m);
    v0.z = __expf(v0.z - m); v0.w = __expf(v0.w - m);
    v1.x = __expf(v1.x - m); v1.y = __expf(v1.y - m);
    v1.z = __expf(v1.z - m); v1.w = __expf(v1.w - m);
    float s = v0.x + v0.y + v0.z + v0.w + v1.x + v1.y + v1.z + v1.w;
#pragma unroll
    for (int o = 32; o; o >>= 1) s += __shfl_xor(s, o);
    float inv = 1.f / s;
    v0.x *= inv; v0.y *= inv; v0.z *= inv; v0.w *= inv;
    v1.x *= inv; v1.y *= inv; v1.z *= inv; v1.w *= inv;
    *(float4*)p = v0;
    *(float4*)(p + 4) = v1;
}

// ===========================================================================
extern "C" void kernel_launch(void* const* d_in, const int* in_sizes, int n_in,
                              void* d_out, int out_size, void* d_ws, size_t ws_size,
                              hipStream_t stream)
{
    const float* data      = (const float*)d_in[0];
    const float* dist      = (const float*)d_in[1];
    const float* cur_dist  = (const float*)d_in[2];
    const float* capacity  = (const float*)d_in[3];
    const float* ninf      = (const float*)d_in[4];
    const float* log_scale = (const float*)d_in[5];
    const float* emb_W     = (const float*)d_in[6];
    const float* emb_b     = (const float*)d_in[7];
    const float* Wq        = (const float*)d_in[8];
    const float* Wk        = (const float*)d_in[9];
    const float* Wv        = (const float*)d_in[10];
    const float* aft_alpha = (const float*)d_in[11];
    const float* n1_w      = (const float*)d_in[12];
    const float* n1_b      = (const float*)d_in[13];
    const float* ffW1      = (const float*)d_in[14];
    const float* ffb1      = (const float*)d_in[15];
    const float* ffW2      = (const float*)d_in[16];
    const float* ffb2      = (const float*)d_in[17];
    const float* n2_w      = (const float*)d_in[18];
    const float* n2_b      = (const float*)d_in[19];
    const float* dWq       = (const float*)d_in[20];
    const float* dWk       = (const float*)d_in[21];
    const float* dWv       = (const float*)d_in[22];
    const float* dec_alpha = (const float*)d_in[23];
    const float* p_alpha   = (const float*)d_in[24];
    float* out = (float*)d_out;

    char* W = (char*)d_ws;
    size_t off = 0;
    auto take = [&](size_t n) { void* pp = W + off; off += (n + 255) & ~(size_t)255; return pp; };
    const size_t SZP = (size_t)B_ * N_ * E_ * 2;   // 8 MB bf16 plane

    u16* xh   = (u16*)take(SZP);
    u16* xl   = (u16*)take(SZP);
    u16* hh   = (u16*)take(SZP);     // decoder: aft hi
    u16* hl   = (u16*)take(SZP);     // decoder: aft lo
    u16* sq16 = (u16*)take(SZP);     // + y2t + pad = 32MB region for ff1
    u16* y2t  = (u16*)take(2 * SZP); // [B][256][512] bf16 = 16 MB
    (void)take(SZP);                 // pad so ff1 (32MB) fits from sq16 base
    float* w2 = (float*)take((size_t)B_ * N_ * 256 * 4);  // 32 MB fp32 (vt/ff2 alias)
    u16* wqt_h = (u16*)take(196608); u16* wqt_l = (u16*)take(196608);
    u16* wkt_h = (u16*)take(196608); u16* wkt_l = (u16*)take(196608);
    u16* wvt_h = (u16*)take(196608); u16* wvt_l = (u16*)take(196608);
    u16* w1t_h = (u16*)take(786432); u16* w1t_l = (u16*)take(786432);
    u16* w2t_h = (u16*)take(786432); u16* w2t_l = (u16*)take(786432);
    u16* dkt_h = (u16*)take(32768);  u16* dkt_l = (u16*)take(32768);
    u16* dvt_h = (u16*)take(32768);  u16* dvt_l = (u16*)take(32768);
    float* gq = (float*)take(32768);
    if (ws_size < off) return;

    u16* vt = (u16*)w2;          // 8MB, dead before w2 written
    u16* ff1 = sq16;             // 32MB spanning sq16+y2t+pad (all dead at FF1 time)
    float* ff2 = w2;             // 16MB, w2 dead after inorm1

    // ---- weight prep ----
    wprep_k<<<dim3(4, 4, 6), 256, 0, stream>>>(Wq, wqt_h, wqt_l, 128, 128);
    wprep_k<<<dim3(4, 4, 6), 256, 0, stream>>>(Wk, wkt_h, wkt_l, 128, 128);
    wprep_k<<<dim3(4, 4, 6), 256, 0, stream>>>(Wv, wvt_h, wvt_l, 128, 128);
    wprep_k<<<dim3(4, 16, 6), 256, 0, stream>>>(ffW1, w1t_h, w1t_l, 128, 512);
    wprep_k<<<dim3(16, 4, 6), 256, 0, stream>>>(ffW2, w2t_h, w2t_l, 512, 128);
    wprep_k<<<dim3(4, 4, 1), 256, 0, stream>>>(dWk, dkt_h, dkt_l, 128, 128);
    wprep_k<<<dim3(4, 4, 1), 256, 0, stream>>>(dWv, dvt_h, dvt_l, 128, 128);

    embed_k<<<16384, 256, 0, stream>>>(data, emb_W, emb_b, xh, xl);

    for (int l = 0; l < L_; ++l) {
        QP qp{};
        qp.A0 = xh; qp.A1 = xl;
        qp.bh0 = wqt_h + l * 16384; qp.bl0 = wqt_l + l * 16384;
        qp.bh1 = wvt_h + l * 16384; qp.bl1 = wvt_l + l * 16384;
        qp.bh2 = wkt_h + l * 16384; qp.bl2 = wkt_l + l * 16384;
        qp.sq16 = sq16; qp.vt = vt; qp.y2t = y2t;
        qvk_k<0><<<dim3(512, 3), 256, 0, stream>>>(qp);
        ekv_k<<<2048, 256, 0, stream>>>(vt, y2t);

        GP gp{};
        gp.A0 = dist; gp.B0 = y2t; gp.Cf = w2;
        gp.s1 = log_scale; gp.s2 = aft_alpha; gp.s2i = l;
        gp.K = 512; gp.lda = 512; gp.ldb = 512;
        gp.sA = 262144; gp.sB = 131072;
        big_k<1, 0><<<dim3(8, 1, 64), 256, 0, stream>>>(gp);

        inorm_k<1><<<dim3(B_, 8), 256, 0, stream>>>(
            xh, xl, sq16, nullptr, w2, n1_w + l * 128, n1_b + l * 128, hh, hl);

        FP fp{};
        fp.A0 = hh; fp.A1 = hl;
        fp.B0 = w1t_h + l * 65536; fp.B1 = w1t_l + l * 65536;
        fp.bias = ffb1 + l * 512; fp.o16 = ff1;
        ffn_k<1><<<dim3(512, 4), 256, 0, stream>>>(fp);

        fp = FP{};
        fp.A0 = ff1;
        fp.B0 = w2t_h + l * 65536; fp.B1 = w2t_l + l * 65536;
        fp.bias = ffb2 + l * 128; fp.of = ff2;
        ffn_k<2><<<dim3(512, 1), 256, 0, stream>>>(fp);

        inorm_k<2><<<dim3(B_, 8), 256, 0, stream>>>(
            hh, hl, nullptr, ff2, nullptr, n2_w + l * 128, n2_b + l * 128, xh, xl);
    }

    // ---- decoder ---- (enc = xh/xl)
    {
        QP qp{};
        qp.A0 = xh; qp.A1 = xl;
        qp.bh0 = dvt_h; qp.bl0 = dvt_l;   // y=0 -> eid1 (vt)
        qp.bh1 = dkt_h; qp.bl1 = dkt_l;   // y=1 -> eid2 (ek)
        qp.vt = vt; qp.y2t = y2t;
        qvk_k<1><<<dim3(512, 2), 256, 0, stream>>>(qp);
        ekv_k<<<2048, 256, 0, stream>>>(vt, y2t);
        gq_k<<<B_, 512, 0, stream>>>(xh, xl, dWq, gq);

        GP gp{};
        gp.A0 = cur_dist; gp.A1 = ninf; gp.B0 = y2t; gp.Cf = w2;
        gp.s1 = log_scale; gp.s2 = dec_alpha; gp.s2i = 0;
        gp.K = 512; gp.lda = 512; gp.ldb = 512;
        gp.sA = 262144; gp.sB = 131072;
        big_k<2, 0><<<dim3(8, 1, 64), 256, 0, stream>>>(gp);

        dec_aft_k<<<16384, 256, 0, stream>>>(gq, capacity, dWq, w2, hh, hl);

        gp = GP{};
        gp.A0 = hh; gp.A1 = hl; gp.B0 = xh; gp.B1 = xl;
        gp.Cf = out; gp.cd = cur_dist; gp.cm = ninf;
        gp.s1 = log_scale; gp.s2 = p_alpha; gp.s2i = 0;
        gp.K = 128; gp.lda = 128; gp.ldb = 128;
        gp.sA = 65536; gp.sB = 65536;
        big_k<0, 1><<<dim3(8, 2, 64), 256, 0, stream>>>(gp);

        softmax_k<<<8192, 256, 0, stream>>>(out);
    }
}